// Round 4
// baseline (234.917 us; speedup 1.0000x reference)
//
#include <hip/hip_runtime.h>
#include <math.h>

#define BATCH    65536
#define FEAT     512
#define NCLASS   16
#define LAMDA    1.0f
#define LAMDA1   10.0f
#define SCALE    1.0f
#define EPS      1e-9f

constexpr int BLOCK  = 256;
constexpr int GRID   = 4096;
constexpr int NV     = BATCH * (FEAT / 4);     // 8,388,608 float4 elements
constexpr int STRIDE = GRID * BLOCK;           // 1,048,576
constexpr int ITERS  = NV / STRIDE;            // exactly 8

// ---------------------------------------------------------------------------
// Kernel 1: center-loss partial sums.
// R3 lesson: 8-deep unrolled VMEM pipelining alone gained nothing (~78 us);
// suspect = per-iter center gather on the VMEM pipe (L1 thrashed by the x
// stream -> L2 round-trip) + in-loop y s_loads forcing lgkmcnt(0) segments.
// This version: centers staged to LDS (DS pipe, in-order), y scalar loads
// hoisted before the barrier. Main loop = pure x streaming + ds_read_b128.
// ---------------------------------------------------------------------------
__global__ __launch_bounds__(BLOCK) void center_loss_kernel(
    const float4* __restrict__ x,        // [BATCH * FEAT/4]
    const int*    __restrict__ y,        // [BATCH]
    const float4* __restrict__ centers4, // [NCLASS * FEAT/4]
    float*        __restrict__ accum)    // ws[0], pre-zeroed
{
    __shared__ float4 cl[NCLASS * (FEAT / 4)];  // 16 x 128 float4 = 32 KB
    __shared__ float  wsum[4];

    const int tid = blockIdx.x * BLOCK + threadIdx.x;
    // wave-uniform sample-row base (wave = 64 consecutive tid inside one
    // 128-aligned chunk; STRIDE % 128 == 0) -> y loads become s_loads.
    const int base_b = __builtin_amdgcn_readfirstlane(tid >> 7);
    const int d4     = tid & 127;

    // Stage all centers into LDS: 2048 float4, 8 per thread, coalesced.
    #pragma unroll
    for (int k = 0; k < 8; ++k)
        cl[threadIdx.x + k * BLOCK] = centers4[threadIdx.x + k * BLOCK];

    // Hoist all 8 class ids (scalar loads complete before the barrier, so
    // the main loop's lgkm traffic is in-order DS reads only).
    int cls[ITERS];
    #pragma unroll
    for (int it = 0; it < ITERS; ++it)
        cls[it] = y[base_b + it * (STRIDE >> 7)];

    __syncthreads();

    float sum = 0.0f;
    #pragma unroll
    for (int it = 0; it < ITERS; ++it) {
        float4 xv = x[tid + it * STRIDE];
        float4 cv = cl[cls[it] * (FEAT / 4) + d4];
        float e0 = xv.x - cv.x;
        float e1 = xv.y - cv.y;
        float e2 = xv.z - cv.z;
        float e3 = xv.w - cv.w;
        sum += e0 * e0 + e1 * e1 + e2 * e2 + e3 * e3;
    }

    // wave (64-lane) shuffle reduction
    #pragma unroll
    for (int off = 32; off > 0; off >>= 1)
        sum += __shfl_down(sum, off, 64);

    const int lane = threadIdx.x & 63;
    const int wid  = threadIdx.x >> 6;
    if (lane == 0) wsum[wid] = sum;
    __syncthreads();
    if (threadIdx.x == 0) {
        atomicAdd(accum, wsum[0] + wsum[1] + wsum[2] + wsum[3]);
    }
}

// ---------------------------------------------------------------------------
// Kernel 2 (single block): 16x16 gram from L2-hot centers + final combine.
// ---------------------------------------------------------------------------
__global__ __launch_bounds__(256) void finalize_kernel(
    const float4* __restrict__ centers4, // [NCLASS * FEAT/4]
    const float*  __restrict__ accum,    // ws[0]
    float*        __restrict__ out)      // [1]
{
    __shared__ float gram[NCLASS][NCLASS];
    const int j = threadIdx.x >> 4;
    const int k = threadIdx.x & 15;
    const float4* cj = centers4 + j * (FEAT / 4);
    const float4* ck = centers4 + k * (FEAT / 4);
    float dot = 0.0f;
    #pragma unroll 8
    for (int i = 0; i < FEAT / 4; ++i) {
        float4 a = cj[i];
        float4 b = ck[i];
        dot += a.x * b.x + a.y * b.y + a.z * b.z + a.w * b.w;
    }
    gram[j][k] = dot;
    __syncthreads();

    if (threadIdx.x == 0) {
        float item1 = 0.0f;
        for (int jj = 0; jj < NCLASS; ++jj) {
            float nj = sqrtf(gram[jj][jj]);
            for (int kk = jj + 1; kk < NCLASS; ++kk) {
                float nk = sqrtf(gram[kk][kk]);
                item1 += gram[jj][kk] / (nj * nk + EPS) + 1.0f;
            }
        }
        float loss_center = 0.5f * accum[0] * (SCALE / (float)BATCH);
        out[0] = LAMDA * (loss_center + LAMDA1 * item1);
    }
}

extern "C" void kernel_launch(void* const* d_in, const int* in_sizes, int n_in,
                              void* d_out, int out_size, void* d_ws, size_t ws_size,
                              hipStream_t stream) {
    const float* x       = (const float*)d_in[0];   // [BATCH, FEAT]
    const int*   y       = (const int*)d_in[1];     // [BATCH]
    const float* centers = (const float*)d_in[2];   // [NCLASS, FEAT]
    float* out   = (float*)d_out;
    float* accum = (float*)d_ws;

    hipMemsetAsync(accum, 0, sizeof(float), stream);

    center_loss_kernel<<<GRID, BLOCK, 0, stream>>>(
        (const float4*)x, y, (const float4*)centers, accum);

    finalize_kernel<<<1, 256, 0, stream>>>((const float4*)centers, accum, out);
}

// Round 5
// 214.830 us; speedup vs baseline: 1.0935x; 1.0935x over previous
//
#include <hip/hip_runtime.h>
#include <math.h>

#define BATCH    65536
#define FEAT     512
#define NCLASS   16
#define LAMDA    1.0f
#define LAMDA1   10.0f
#define SCALE    1.0f
#define EPS      1e-9f

constexpr int BLOCK  = 256;
constexpr int GRID   = 4096;
constexpr int NV     = BATCH * (FEAT / 4);     // 8,388,608 float4 elements
constexpr int STRIDE = GRID * BLOCK;           // 1,048,576
constexpr int ITERS  = NV / STRIDE;            // exactly 8

// ---------------------------------------------------------------------------
// Kernel 1: center-loss partial sums.
// R1/R3/R4 all pinned at ~78 us despite different memory structures ->
// common factor = 4096 same-address device-scope atomicAdds (serialized RMW
// at the coherence point, ~20 ns each ~ 80 us). This version: NO atomics.
// Each block stores its partial to its own ws slot (zero contention);
// finalize reduces the 4096 partials.
// ---------------------------------------------------------------------------
__global__ __launch_bounds__(BLOCK) void center_loss_kernel(
    const float4* __restrict__ x,        // [BATCH * FEAT/4]
    const int*    __restrict__ y,        // [BATCH]
    const float4* __restrict__ centers4, // [NCLASS * FEAT/4]
    float*        __restrict__ partials) // ws: [GRID], one slot per block
{
    const int tid = blockIdx.x * BLOCK + threadIdx.x;

    // wave-uniform sample-row base (wave = 64 consecutive tid inside one
    // 128-aligned chunk; STRIDE % 128 == 0) -> y loads become s_loads.
    const int base_b = __builtin_amdgcn_readfirstlane(tid >> 7);
    const int d4     = tid & 127;

    // Hoist all 8 class ids out of the main loop.
    int cls[ITERS];
    #pragma unroll
    for (int it = 0; it < ITERS; ++it)
        cls[it] = y[base_b + it * (STRIDE >> 7)];

    float sum = 0.0f;
    #pragma unroll
    for (int it = 0; it < ITERS; ++it) {
        float4 xv = x[tid + it * STRIDE];
        float4 cv = centers4[cls[it] * (FEAT / 4) + d4];
        float e0 = xv.x - cv.x;
        float e1 = xv.y - cv.y;
        float e2 = xv.z - cv.z;
        float e3 = xv.w - cv.w;
        sum += e0 * e0 + e1 * e1 + e2 * e2 + e3 * e3;
    }

    // wave (64-lane) shuffle reduction
    #pragma unroll
    for (int off = 32; off > 0; off >>= 1)
        sum += __shfl_down(sum, off, 64);

    __shared__ float wsum[4];
    const int lane = threadIdx.x & 63;
    const int wid  = threadIdx.x >> 6;
    if (lane == 0) wsum[wid] = sum;
    __syncthreads();
    if (threadIdx.x == 0) {
        partials[blockIdx.x] = wsum[0] + wsum[1] + wsum[2] + wsum[3];
    }
}

// ---------------------------------------------------------------------------
// Kernel 2 (single block): reduce 4096 partials + 16x16 gram + combine.
// ---------------------------------------------------------------------------
__global__ __launch_bounds__(256) void finalize_kernel(
    const float4* __restrict__ centers4, // [NCLASS * FEAT/4]
    const float*  __restrict__ partials, // [GRID]
    float*        __restrict__ out)      // [1]
{
    // ---- reduce the 4096 per-block partials (16 per thread, coalesced) ----
    float psum = 0.0f;
    #pragma unroll
    for (int k = 0; k < GRID / 256; ++k)
        psum += partials[threadIdx.x + k * 256];
    #pragma unroll
    for (int off = 32; off > 0; off >>= 1)
        psum += __shfl_down(psum, off, 64);

    __shared__ float wsum[4];
    const int lane = threadIdx.x & 63;
    const int wid  = threadIdx.x >> 6;
    if (lane == 0) wsum[wid] = psum;

    // ---- 16x16 gram from L2-hot centers ----
    __shared__ float gram[NCLASS][NCLASS];
    const int j = threadIdx.x >> 4;
    const int k = threadIdx.x & 15;
    const float4* cj = centers4 + j * (FEAT / 4);
    const float4* ck = centers4 + k * (FEAT / 4);
    float dot = 0.0f;
    #pragma unroll 8
    for (int i = 0; i < FEAT / 4; ++i) {
        float4 a = cj[i];
        float4 b = ck[i];
        dot += a.x * b.x + a.y * b.y + a.z * b.z + a.w * b.w;
    }
    gram[j][k] = dot;
    __syncthreads();

    if (threadIdx.x == 0) {
        float item1 = 0.0f;
        for (int jj = 0; jj < NCLASS; ++jj) {
            float nj = sqrtf(gram[jj][jj]);
            for (int kk = jj + 1; kk < NCLASS; ++kk) {
                float nk = sqrtf(gram[kk][kk]);
                item1 += gram[jj][kk] / (nj * nk + EPS) + 1.0f;
            }
        }
        float total = wsum[0] + wsum[1] + wsum[2] + wsum[3];
        float loss_center = 0.5f * total * (SCALE / (float)BATCH);
        out[0] = LAMDA * (loss_center + LAMDA1 * item1);
    }
}

extern "C" void kernel_launch(void* const* d_in, const int* in_sizes, int n_in,
                              void* d_out, int out_size, void* d_ws, size_t ws_size,
                              hipStream_t stream) {
    const float* x        = (const float*)d_in[0];   // [BATCH, FEAT]
    const int*   y        = (const int*)d_in[1];     // [BATCH]
    const float* centers  = (const float*)d_in[2];   // [NCLASS, FEAT]
    float* out      = (float*)d_out;
    float* partials = (float*)d_ws;                  // 4096 floats, all written

    center_loss_kernel<<<GRID, BLOCK, 0, stream>>>(
        (const float4*)x, y, (const float4*)centers, partials);

    finalize_kernel<<<1, 256, 0, stream>>>((const float4*)centers, partials, out);
}

// Round 6
// 206.487 us; speedup vs baseline: 1.1377x; 1.0404x over previous
//
#include <hip/hip_runtime.h>
#include <math.h>

#define BATCH    65536
#define FEAT     512
#define NCLASS   16
#define LAMDA    1.0f
#define LAMDA1   10.0f
#define SCALE    1.0f
#define EPS      1e-9f

constexpr int BLOCK  = 256;
constexpr int GRID   = 4096;
constexpr int NV     = BATCH * (FEAT / 4);     // 8,388,608 float4 elements
constexpr int STRIDE = GRID * BLOCK;           // 1,048,576
constexpr int ITERS  = NV / STRIDE;            // exactly 8

// clang ext-vector float4 so __builtin_nontemporal_load accepts it directly.
typedef float f4v __attribute__((ext_vector_type(4)));

// ---------------------------------------------------------------------------
// Kernel 1: center-loss partial sums.
// R5 lesson: atomics were only part of the floor (78 -> ~60 us). Theory now:
// the 128 MiB x stream thrashes L1 (32 KiB) and per-XCD L2 (4 MiB), so the
// per-iteration center gather (~128 MiB logical) keeps missing to L3 ->
// kernel is Infinity-Cache-BW bound on ~2x traffic. Fix: NON-TEMPORAL loads
// for x (no L1/L2 allocation) so the 32-KB centers table stays cache-hot.
// ---------------------------------------------------------------------------
__global__ __launch_bounds__(BLOCK) void center_loss_kernel(
    const f4v* __restrict__ x,         // [BATCH * FEAT/4]
    const int* __restrict__ y,         // [BATCH]
    const f4v* __restrict__ centers4,  // [NCLASS * FEAT/4]
    float*     __restrict__ partials)  // ws: [GRID], one slot per block
{
    const int tid = blockIdx.x * BLOCK + threadIdx.x;

    // wave-uniform sample-row base (wave = 64 consecutive tid inside one
    // 128-aligned chunk; STRIDE % 128 == 0) -> y loads become s_loads.
    const int base_b = __builtin_amdgcn_readfirstlane(tid >> 7);
    const int d4     = tid & 127;

    // Hoist all 8 class ids out of the main loop.
    int cls[ITERS];
    #pragma unroll
    for (int it = 0; it < ITERS; ++it)
        cls[it] = y[base_b + it * (STRIDE >> 7)];

    float sum = 0.0f;
    #pragma unroll
    for (int it = 0; it < ITERS; ++it) {
        f4v xv = __builtin_nontemporal_load(&x[tid + it * STRIDE]);  // nt: bypass L1/L2 alloc
        f4v cv = centers4[cls[it] * (FEAT / 4) + d4];                // stays cache-hot
        f4v e  = xv - cv;
        sum += e.x * e.x + e.y * e.y + e.z * e.z + e.w * e.w;
    }

    // wave (64-lane) shuffle reduction
    #pragma unroll
    for (int off = 32; off > 0; off >>= 1)
        sum += __shfl_down(sum, off, 64);

    __shared__ float wsum[4];
    const int lane = threadIdx.x & 63;
    const int wid  = threadIdx.x >> 6;
    if (lane == 0) wsum[wid] = sum;
    __syncthreads();
    if (threadIdx.x == 0) {
        partials[blockIdx.x] = wsum[0] + wsum[1] + wsum[2] + wsum[3];
    }
}

// ---------------------------------------------------------------------------
// Kernel 2 (single block): reduce 4096 partials + 16x16 gram + combine.
// ---------------------------------------------------------------------------
__global__ __launch_bounds__(256) void finalize_kernel(
    const f4v*   __restrict__ centers4, // [NCLASS * FEAT/4]
    const float* __restrict__ partials, // [GRID]
    float*       __restrict__ out)      // [1]
{
    // ---- reduce the 4096 per-block partials (16 per thread, coalesced) ----
    float psum = 0.0f;
    #pragma unroll
    for (int k = 0; k < GRID / 256; ++k)
        psum += partials[threadIdx.x + k * 256];
    #pragma unroll
    for (int off = 32; off > 0; off >>= 1)
        psum += __shfl_down(psum, off, 64);

    __shared__ float wsum[4];
    const int lane = threadIdx.x & 63;
    const int wid  = threadIdx.x >> 6;
    if (lane == 0) wsum[wid] = psum;

    // ---- 16x16 gram from L2-hot centers ----
    __shared__ float gram[NCLASS][NCLASS];
    const int j = threadIdx.x >> 4;
    const int k = threadIdx.x & 15;
    const f4v* cj = centers4 + j * (FEAT / 4);
    const f4v* ck = centers4 + k * (FEAT / 4);
    float dot = 0.0f;
    #pragma unroll 8
    for (int i = 0; i < FEAT / 4; ++i) {
        f4v a = cj[i];
        f4v b = ck[i];
        dot += a.x * b.x + a.y * b.y + a.z * b.z + a.w * b.w;
    }
    gram[j][k] = dot;
    __syncthreads();

    if (threadIdx.x == 0) {
        float item1 = 0.0f;
        for (int jj = 0; jj < NCLASS; ++jj) {
            float nj = sqrtf(gram[jj][jj]);
            for (int kk = jj + 1; kk < NCLASS; ++kk) {
                float nk = sqrtf(gram[kk][kk]);
                item1 += gram[jj][kk] / (nj * nk + EPS) + 1.0f;
            }
        }
        float total = wsum[0] + wsum[1] + wsum[2] + wsum[3];
        float loss_center = 0.5f * total * (SCALE / (float)BATCH);
        out[0] = LAMDA * (loss_center + LAMDA1 * item1);
    }
}

extern "C" void kernel_launch(void* const* d_in, const int* in_sizes, int n_in,
                              void* d_out, int out_size, void* d_ws, size_t ws_size,
                              hipStream_t stream) {
    const float* x       = (const float*)d_in[0];   // [BATCH, FEAT]
    const int*   y       = (const int*)d_in[1];     // [BATCH]
    const float* centers = (const float*)d_in[2];   // [NCLASS, FEAT]
    float* out      = (float*)d_out;
    float* partials = (float*)d_ws;                 // 4096 floats, all written

    center_loss_kernel<<<GRID, BLOCK, 0, stream>>>(
        (const f4v*)x, y, (const f4v*)centers, partials);

    finalize_kernel<<<1, 256, 0, stream>>>((const f4v*)centers, partials, out);
}